// Round 8
// baseline (330.374 us; speedup 1.0000x reference)
//
#include <hip/hip_runtime.h>
#include <hip/hip_fp16.h>

#define SDIM 1024

typedef _Float16 f16;
typedef _Float16 f16x8 __attribute__((ext_vector_type(8)));
typedef __attribute__((ext_vector_type(4))) float f32x4;

union FragH { unsigned int u[4]; f16x8 f; };
union H2U  { unsigned int u; __half2 h; };

// packed-f16 tanh-gelu, variant-ablated for diagnostics:
// V0 = full (5 pk-VALU prefix + 2 exp + 2 add + 2 rcp + pack + mul)
// V1 = passthrough g=t   (drops prefix tail AND trans tail; keeps the u+v add)
// V2 = g=Z               (keeps 5 pk-VALU prefix, drops the trans tail)
template<int V>
__device__ __forceinline__ unsigned int addgelu_pair(unsigned int au, unsigned int bu) {
    const __half2 k044 = __float2half2_rn(0.044715f);
    const __half2 one  = __float2half2_rn(1.0f);
    const __half2 cz   = __float2half2_rn(-2.3022082f);
    H2U A, B, T, Z, R, G;
    A.u = au; B.u = bu;
    __half2 t  = __hadd2(A.h, B.h);
    if (V == 1) { T.h = t; return T.u; }
    __half2 t2 = __hmul2(t, t);
    __half2 pl = __hfma2(t2, k044, one);
    Z.h = __hmul2(__hmul2(t, cz), pl);
    if (V == 2) { return Z.u; }
    unsigned int zh = Z.u >> 16;
    unsigned int el, eh, dl, dh, rl, rh, ru;
    asm("v_exp_f16 %0, %1"      : "=v"(el) : "v"(Z.u));
    asm("v_exp_f16 %0, %1"      : "=v"(eh) : "v"(zh));
    asm("v_add_f16 %0, %1, 1.0" : "=v"(dl) : "v"(el));
    asm("v_add_f16 %0, %1, 1.0" : "=v"(dh) : "v"(eh));
    asm("v_rcp_f16 %0, %1"      : "=v"(rl) : "v"(dl));
    asm("v_rcp_f16 %0, %1"      : "=v"(rh) : "v"(dh));
    asm("v_pack_b32_f16 %0, %1, %2" : "=v"(ru) : "v"(rl), "v"(rh));
    R.u = ru;
    G.h = __hmul2(t, R.h);
    return G.u;
}

// ---------------- Kernel 1: u[b,s,64] = xc@W1[:32] + b1 ; v = xc@W1[32:] (f16 out) -----
__global__ __launch_bounds__(256) void compute_uv(
    const float* __restrict__ x, const float* __restrict__ Wc,
    const float* __restrict__ bc, const float* __restrict__ W1,
    const float* __restrict__ b1, f16* __restrict__ u, f16* __restrict__ v)
{
    __shared__ float xrow[4 * 1024];
    __shared__ float part[4 * 8 * 32];
    __shared__ float xc[4 * 32];
    const int tid = threadIdx.x;
    const size_t bs0 = (size_t)blockIdx.x * 4;

    const float4* xin = (const float4*)(x + bs0 * 1024);
    #pragma unroll
    for (int it = 0; it < 4; ++it)
        ((float4*)xrow)[it * 256 + tid] = xin[it * 256 + tid];
    __syncthreads();

    {
        const int c = tid & 31, p = tid >> 5;
        float acc[4] = {0.f, 0.f, 0.f, 0.f};
        #pragma unroll 4
        for (int dd = 0; dd < 128; ++dd) {
            const int d = p * 128 + dd;
            const float wv = Wc[d * 32 + c];
            #pragma unroll
            for (int r = 0; r < 4; ++r)
                acc[r] = __builtin_fmaf(xrow[r * 1024 + d], wv, acc[r]);
        }
        #pragma unroll
        for (int r = 0; r < 4; ++r)
            part[r * 256 + p * 32 + c] = acc[r];
    }
    __syncthreads();
    if (tid < 128) {
        const int r = tid >> 5, c = tid & 31;
        float s = bc[c];
        #pragma unroll
        for (int p = 0; p < 8; ++p) s += part[r * 256 + p * 32 + c];
        xc[r * 32 + c] = s;
    }
    __syncthreads();
    {
        const int h = tid & 63;
        const int rr = tid >> 6;
        float ua = b1[h], va = 0.0f;
        #pragma unroll
        for (int cc = 0; cc < 32; ++cc) {
            const float xv = xc[rr * 32 + cc];
            ua = __builtin_fmaf(xv, W1[cc * 64 + h], ua);
            va = __builtin_fmaf(xv, W1[(32 + cc) * 64 + h], va);
        }
        u[(bs0 + rr) * 64 + h] = (f16)ua;
        v[(bs0 + rr) * 64 + h] = (f16)va;
    }
}

// ---------------- Kernel 2 (R5 structure, + rep loop for counter visibility) ----------
// out[b,h,i,j] = sum_k gelu(u[i,k]+v[j,k]) * W2[k,h] + b2[h]
// D = G_i (16j x 64k) @ W2 (64k x 16h); D col = lane&15 = h, row = j-in-tile.
template<int V>
__global__ __launch_bounds__(256, 2) void prg_rep(
    const f16* __restrict__ u, const f16* __restrict__ v,
    const float* __restrict__ W2, const float* __restrict__ b2,
    float* __restrict__ out, int reps)
{
    const int tid  = threadIdx.x;
    const int lane = tid & 63;
    const int w    = tid >> 6;
    const int jb   = blockIdx.x * 64;
    const int ib   = blockIdx.y * 32;
    const int b    = blockIdx.z;

    __shared__ f16 u_lds[32][64];   // 4 KB

    {
        const int row = tid >> 3;
        const int col = (tid & 7) * 8;
        *(uint4*)&u_lds[row][col] =
            *(const uint4*)(u + ((size_t)(b * SDIM + ib + row) * 64 + col));
    }

    const int lg = lane >> 4;   // k-group 0..3
    const int lr = lane & 15;   // A row (j) / B+D col (h)
    const int k0 = lg * 8;

    const int jA = jb + w * 16 + lr;
    const f16* vp = v + ((size_t)(b * SDIM + jA) * 64);
    const uint4 vlo = *(const uint4*)(vp + k0);
    const uint4 vhi = *(const uint4*)(vp + k0 + 32);

    FragH w2lo, w2hi;
    #pragma unroll
    for (int e = 0; e < 4; ++e) {
        H2U a, c;
        a.h = __floats2half2_rn(W2[(k0 + 2*e) * 16 + lr],      W2[(k0 + 2*e + 1) * 16 + lr]);
        c.h = __floats2half2_rn(W2[(k0 + 32 + 2*e) * 16 + lr], W2[(k0 + 32 + 2*e + 1) * 16 + lr]);
        w2lo.u[e] = a.u;
        w2hi.u[e] = c.u;
    }

    const float b2h = b2[lr];

    __syncthreads();

    float* ob = out + ((size_t)(b * 16 + lr) * SDIM + ib) * SDIM + (jb + w * 16 + lg * 4);

    for (int rep = 0; rep < reps; ++rep) {
        #pragma unroll 2
        for (int il = 0; il < 32; ++il) {
            const uint4 alo = *(const uint4*)&u_lds[il][k0];
            const uint4 ahi = *(const uint4*)&u_lds[il][k0 + 32];

            FragH glo, ghi;
            glo.u[0] = addgelu_pair<V>(alo.x, vlo.x);
            glo.u[1] = addgelu_pair<V>(alo.y, vlo.y);
            glo.u[2] = addgelu_pair<V>(alo.z, vlo.z);
            glo.u[3] = addgelu_pair<V>(alo.w, vlo.w);
            ghi.u[0] = addgelu_pair<V>(ahi.x, vhi.x);
            ghi.u[1] = addgelu_pair<V>(ahi.y, vhi.y);
            ghi.u[2] = addgelu_pair<V>(ahi.z, vhi.z);
            ghi.u[3] = addgelu_pair<V>(ahi.w, vhi.w);

            f32x4 acc = {b2h, b2h, b2h, b2h};
            acc = __builtin_amdgcn_mfma_f32_16x16x32_f16(glo.f, w2lo.f, acc, 0, 0, 0);
            acc = __builtin_amdgcn_mfma_f32_16x16x32_f16(ghi.f, w2hi.f, acc, 0, 0, 0);

            *(float4*)(ob + (size_t)il * SDIM) = *(float4*)&acc;
        }
    }
}

extern "C" void kernel_launch(void* const* d_in, const int* in_sizes, int n_in,
                              void* d_out, int out_size, void* d_ws, size_t ws_size,
                              hipStream_t stream) {
    const float* x  = (const float*)d_in[0];
    const float* Wc = (const float*)d_in[1];
    const float* bc = (const float*)d_in[2];
    const float* W1 = (const float*)d_in[3];
    const float* b1 = (const float*)d_in[4];
    const float* W2 = (const float*)d_in[5];
    const float* b2 = (const float*)d_in[6];
    float* out = (float*)d_out;

    f16* u = (f16*)d_ws;
    f16* v = u + 2 * SDIM * 64;

    compute_uv<<<dim3(512), dim3(256), 0, stream>>>(x, Wc, bc, W1, b1, u, v);

    const dim3 grid(16, 32, 2), blk(256);
    // Diagnostic dispatches (wrong output values, overwritten below; reps sized so
    // each dispatch exceeds the ~82 us harness fills and surfaces in top-5 counters):
    prg_rep<1><<<grid, blk, 0, stream>>>(u, v, W2, b2, out, 5);  // no gelu (floor)
    prg_rep<2><<<grid, blk, 0, stream>>>(u, v, W2, b2, out, 3);  // VALU prefix only
    prg_rep<0><<<grid, blk, 0, stream>>>(u, v, W2, b2, out, 3);  // full, rep-scaled
    // Final correct pass (R5-equivalent):
    prg_rep<0><<<grid, blk, 0, stream>>>(u, v, W2, b2, out, 1);
}

// Round 10
// 49.673 us; speedup vs baseline: 6.6510x; 6.6510x over previous
//
#include <hip/hip_runtime.h>
#include <hip/hip_fp16.h>

#define SDIM 1024

typedef _Float16 f16;
typedef _Float16 f16x2v __attribute__((ext_vector_type(2)));
typedef _Float16 f16x8 __attribute__((ext_vector_type(8)));
typedef __attribute__((ext_vector_type(4))) float f32x4;

union FragH { unsigned int u[4]; f16x8 f; };
union H2U  { unsigned int u; __half2 h; f16x2v v; };

// packed-f16 tanh-gelu via trans-free polynomial:
// g = t*(0.5 + 0.5*tc*W(tc^2)), tc = clamp(t,-3,3),
// W(s) = tanh(0.797885*t + 0.0356774*t^3)/t as deg-5 poly in x = s*(2/9)-1
// (Chebyshev-Lobatto fit on s in [0,9], |W err| ~1e-4 -> |g err| <= ~5e-4).
// 13 pk-VALU slots, ZERO trans ops (old path: 4 quarter-rate trans = 64% of cycles).
__device__ __forceinline__ unsigned int addgelu_pair(unsigned int au, unsigned int bu) {
    const __half2 kC5  = __float2half2_rn(-0.006912f);
    const __half2 kC4  = __float2half2_rn( 0.019336f);
    const __half2 kC3  = __float2half2_rn(-0.040316f);
    const __half2 kC2  = __float2half2_rn( 0.090220f);
    const __half2 kC1  = __float2half2_rn(-0.185452f);
    const __half2 kC0  = __float2half2_rn( 0.455649f);
    const __half2 kXA  = __float2half2_rn( 0.2222222f);   // 2/9
    const __half2 kXB  = __float2half2_rn(-1.0f);
    const __half2 kHalf= __float2half2_rn( 0.5f);
    const f16x2v vHi = { (f16)3.0f, (f16)3.0f };
    const f16x2v vLo = { (f16)-3.0f, (f16)-3.0f };
    H2U A, B, T, C, G;
    A.u = au; B.u = bu;
    __half2 t  = __hadd2(A.h, B.h);          // pk_add
    T.h = t;
    C.v = __builtin_elementwise_min(__builtin_elementwise_max(T.v, vLo), vHi); // pk_max, pk_min
    __half2 tc = C.h;
    __half2 s  = __hmul2(tc, tc);            // pk_mul
    __half2 x  = __hfma2(s, kXA, kXB);       // pk_fma
    __half2 w  = __hfma2(kC5, x, kC4);       // 5x pk_fma Horner
    w = __hfma2(w, x, kC3);
    w = __hfma2(w, x, kC2);
    w = __hfma2(w, x, kC1);
    w = __hfma2(w, x, kC0);
    __half2 m  = __hmul2(tc, w);             // pk_mul
    __half2 sg = __hfma2(m, kHalf, kHalf);   // pk_fma -> sigma in (0,1)
    G.h = __hmul2(t, sg);                    // pk_mul
    return G.u;
}

// ---------------- Kernel 1: u[b,s,64] = xc@W1[:32] + b1 ; v = xc@W1[32:] (f16 out) -----
__global__ __launch_bounds__(256) void compute_uv(
    const float* __restrict__ x, const float* __restrict__ Wc,
    const float* __restrict__ bc, const float* __restrict__ W1,
    const float* __restrict__ b1, f16* __restrict__ u, f16* __restrict__ v)
{
    __shared__ float xrow[4 * 1024];
    __shared__ float part[4 * 8 * 32];
    __shared__ float xc[4 * 32];
    const int tid = threadIdx.x;
    const size_t bs0 = (size_t)blockIdx.x * 4;

    const float4* xin = (const float4*)(x + bs0 * 1024);
    #pragma unroll
    for (int it = 0; it < 4; ++it)
        ((float4*)xrow)[it * 256 + tid] = xin[it * 256 + tid];
    __syncthreads();

    {
        const int c = tid & 31, p = tid >> 5;
        float acc[4] = {0.f, 0.f, 0.f, 0.f};
        #pragma unroll 4
        for (int dd = 0; dd < 128; ++dd) {
            const int d = p * 128 + dd;
            const float wv = Wc[d * 32 + c];
            #pragma unroll
            for (int r = 0; r < 4; ++r)
                acc[r] = __builtin_fmaf(xrow[r * 1024 + d], wv, acc[r]);
        }
        #pragma unroll
        for (int r = 0; r < 4; ++r)
            part[r * 256 + p * 32 + c] = acc[r];
    }
    __syncthreads();
    if (tid < 128) {
        const int r = tid >> 5, c = tid & 31;
        float s = bc[c];
        #pragma unroll
        for (int p = 0; p < 8; ++p) s += part[r * 256 + p * 32 + c];
        xc[r * 32 + c] = s;
    }
    __syncthreads();
    {
        const int h = tid & 63;
        const int rr = tid >> 6;
        float ua = b1[h], va = 0.0f;
        #pragma unroll
        for (int cc = 0; cc < 32; ++cc) {
            const float xv = xc[rr * 32 + cc];
            ua = __builtin_fmaf(xv, W1[cc * 64 + h], ua);
            va = __builtin_fmaf(xv, W1[(32 + cc) * 64 + h], va);
        }
        u[(bs0 + rr) * 64 + h] = (f16)ua;
        v[(bs0 + rr) * 64 + h] = (f16)va;
    }
}

// ---------------- Kernel 2: out[b,h,i,j] = sum_k gelu(u[i,k]+v[j,k]) * W2[k,h] + b2[h] --
// D = G_i (16j x 64k) @ W2 (64k x 16h); D col = lane&15 = h, row = j-in-tile
// -> one dwordx4 store per il. Tile 16 i x 64 j; grid (16,64,2) = 2048 blocks
// (8 blocks/CU at VGPR~32 -> ~full occupancy for VALU issue packing).
__global__ __launch_bounds__(256) void prg_main(
    const f16* __restrict__ u, const f16* __restrict__ v,
    const float* __restrict__ W2, const float* __restrict__ b2,
    float* __restrict__ out)
{
    const int tid  = threadIdx.x;
    const int lane = tid & 63;
    const int w    = tid >> 6;
    const int jb   = blockIdx.x * 64;
    const int ib   = blockIdx.y * 16;
    const int b    = blockIdx.z;

    __shared__ f16 u_lds[16][64];   // 2 KB

    if (tid < 128) {
        const int row = tid >> 3;
        const int col = (tid & 7) * 8;
        *(uint4*)&u_lds[row][col] =
            *(const uint4*)(u + ((size_t)(b * SDIM + ib + row) * 64 + col));
    }

    const int lg = lane >> 4;   // k-group 0..3
    const int lr = lane & 15;   // A row (j) / B+D col (h)
    const int k0 = lg * 8;

    const int jA = jb + w * 16 + lr;
    const f16* vp = v + ((size_t)(b * SDIM + jA) * 64);
    const uint4 vlo = *(const uint4*)(vp + k0);
    const uint4 vhi = *(const uint4*)(vp + k0 + 32);

    FragH w2lo, w2hi;
    #pragma unroll
    for (int e = 0; e < 4; ++e) {
        H2U a, c;
        a.h = __floats2half2_rn(W2[(k0 + 2*e) * 16 + lr],      W2[(k0 + 2*e + 1) * 16 + lr]);
        c.h = __floats2half2_rn(W2[(k0 + 32 + 2*e) * 16 + lr], W2[(k0 + 32 + 2*e + 1) * 16 + lr]);
        w2lo.u[e] = a.u;
        w2hi.u[e] = c.u;
    }

    const float b2h = b2[lr];

    __syncthreads();

    float* ob = out + ((size_t)(b * 16 + lr) * SDIM + ib) * SDIM + (jb + w * 16 + lg * 4);

    #pragma unroll 4
    for (int il = 0; il < 16; ++il) {
        const uint4 alo = *(const uint4*)&u_lds[il][k0];
        const uint4 ahi = *(const uint4*)&u_lds[il][k0 + 32];

        FragH glo, ghi;
        glo.u[0] = addgelu_pair(alo.x, vlo.x);
        glo.u[1] = addgelu_pair(alo.y, vlo.y);
        glo.u[2] = addgelu_pair(alo.z, vlo.z);
        glo.u[3] = addgelu_pair(alo.w, vlo.w);
        ghi.u[0] = addgelu_pair(ahi.x, vhi.x);
        ghi.u[1] = addgelu_pair(ahi.y, vhi.y);
        ghi.u[2] = addgelu_pair(ahi.z, vhi.z);
        ghi.u[3] = addgelu_pair(ahi.w, vhi.w);

        f32x4 acc = {b2h, b2h, b2h, b2h};
        acc = __builtin_amdgcn_mfma_f32_16x16x32_f16(glo.f, w2lo.f, acc, 0, 0, 0);
        acc = __builtin_amdgcn_mfma_f32_16x16x32_f16(ghi.f, w2hi.f, acc, 0, 0, 0);

        *(float4*)(ob + (size_t)il * SDIM) = *(float4*)&acc;
    }
}

extern "C" void kernel_launch(void* const* d_in, const int* in_sizes, int n_in,
                              void* d_out, int out_size, void* d_ws, size_t ws_size,
                              hipStream_t stream) {
    const float* x  = (const float*)d_in[0];
    const float* Wc = (const float*)d_in[1];
    const float* bc = (const float*)d_in[2];
    const float* W1 = (const float*)d_in[3];
    const float* b1 = (const float*)d_in[4];
    const float* W2 = (const float*)d_in[5];
    const float* b2 = (const float*)d_in[6];
    float* out = (float*)d_out;

    f16* u = (f16*)d_ws;
    f16* v = u + 2 * SDIM * 64;

    compute_uv<<<dim3(512), dim3(256), 0, stream>>>(x, Wc, bc, W1, b1, u, v);
    prg_main<<<dim3(16, 64, 2), dim3(256), 0, stream>>>(u, v, W2, b2, out);
}